// Round 2
// baseline (2580.570 us; speedup 1.0000x reference)
//
#include <hip/hip_runtime.h>
#include <hip/hip_bf16.h>
#include <math.h>

constexpr int B = 64, S = 1024, H = 1024;
constexpr int TS = 32;         // s-rows per block in k_energy
constexpr int TO = 256;        // o-columns per pass
constexpr int NPASS = H / TO;  // 4

// ---------------------------------------------------------------------------
// Kernel 1: hb[b][o] = attn_b[o] + sum_h hidden[b,h] * attn_W[o, h]
// One 64-lane wave per (b,o); 4 waves per block.
// ---------------------------------------------------------------------------
__global__ __launch_bounds__(256) void k_hproj(const float* __restrict__ hidden,
                                               const float* __restrict__ attn_W,
                                               const float* __restrict__ attn_b,
                                               float* __restrict__ hb) {
    int wid  = blockIdx.x * 4 + (threadIdx.x >> 6);
    int lane = threadIdx.x & 63;
    int b = wid >> 10;
    int o = wid & 1023;
    const float* hrow = hidden + (size_t)b * H;
    const float* wrow = attn_W + (size_t)o * (2 * H);   // Wh part: cols 0..H-1
    float acc = 0.f;
#pragma unroll
    for (int k = 0; k < 4; ++k) {
        int idx = lane * 4 + k * 256;                   // coalesced float4 per instr
        float4 hv = *(const float4*)(hrow + idx);
        float4 wv = *(const float4*)(wrow + idx);
        acc += hv.x * wv.x + hv.y * wv.y + hv.z * wv.z + hv.w * wv.w;
    }
#pragma unroll
    for (int off = 32; off > 0; off >>= 1) acc += __shfl_down(acc, off, 64);
    if (lane == 0) hb[(size_t)b * H + o] = acc + attn_b[o];
}

// ---------------------------------------------------------------------------
// Kernel 2: fused e_proj GEMM + tanh + dot(v_W) + mask -> raw scores
// Block = (s-tile of 32, b). 512 threads.
// enc tile (32 x 1024 f32 = 128KB) lives in LDS, XOR-swizzled per float4:
//   physical quad index = hq ^ (s & 7)   -> conflict-free ds_read_b128
// We (attn_W[:, H:]) streamed from global (L2/L3 resident, 4MB).
// Each thread: acc[4 s][4 o]; o covered in 4 passes of 256.
// ---------------------------------------------------------------------------
__global__ __launch_bounds__(512) void k_energy(const float* __restrict__ enc,
                                                const float* __restrict__ attn_W,
                                                const float* __restrict__ v_W,
                                                const float* __restrict__ hb,
                                                const int* __restrict__ mask,
                                                float* __restrict__ scores) {
    __shared__ float encT[TS * H];     // 128 KB, swizzled
    __shared__ float hbs[H];           // 4 KB
    __shared__ float red[TS][65];      // 8.3 KB reduction scratch

    const int b  = blockIdx.y;
    const int s0 = blockIdx.x * TS;
    const int tid = threadIdx.x;

    // stage hb row for this b
    for (int i = tid; i < H; i += 512) hbs[i] = hb[(size_t)b * H + i];

    // stage enc tile: rows s0..s0+31, swizzled.
    // 512 threads: rowgroup = tid>>5 (0..15), 32 lanes per row, 2 row passes.
    {
        const int l = tid & 31;
#pragma unroll
        for (int rr = 0; rr < 2; ++rr) {
            const int r = (tid >> 5) + rr * 16;
            const float* gsrc = enc + ((size_t)(s0 + r) * B + b) * H;
#pragma unroll
            for (int k = 0; k < 8; ++k) {
                int hq = l + 32 * k;
                float4 v = *(const float4*)(gsrc + hq * 4);
                *(float4*)(&encT[r * H + ((hq ^ (r & 7)) << 2)]) = v;
            }
        }
    }
    __syncthreads();

    const int sq = tid & 7;        // s = sq + 8*i  (so s&7 == sq, swizzle uniform per thread)
    const int oq = tid >> 3;       // 0..63, o = pass*TO + oq*4 + j

    float partial[4] = {0.f, 0.f, 0.f, 0.f};

    for (int pass = 0; pass < NPASS; ++pass) {
        float acc[4][4] = {};
        const int ob = pass * TO + oq * 4;
        const float* w0 = attn_W + (size_t)ob * (2 * H) + H;   // We part

#pragma unroll 2
        for (int hq = 0; hq < H / 4; ++hq) {
            float4 wv[4];
#pragma unroll
            for (int j = 0; j < 4; ++j)
                wv[j] = *(const float4*)(w0 + (size_t)j * (2 * H) + hq * 4);
#pragma unroll
            for (int i = 0; i < 4; ++i) {
                const int s = sq + 8 * i;
                float4 ev = *(const float4*)(&encT[s * H + ((hq ^ sq) << 2)]);
#pragma unroll
                for (int j = 0; j < 4; ++j) {
                    acc[i][j] += ev.x * wv[j].x + ev.y * wv[j].y
                               + ev.z * wv[j].z + ev.w * wv[j].w;
                }
            }
        }
        // epilogue for this o-pass: tanh + weight by v_W
#pragma unroll
        for (int j = 0; j < 4; ++j) {
            const int o = ob + j;
            const float vw  = v_W[o];
            const float hbv = hbs[o];
#pragma unroll
            for (int i = 0; i < 4; ++i)
                partial[i] += vw * tanhf(acc[i][j] + hbv);
        }
    }

    // block reduction over the 64 o-quads per s
#pragma unroll
    for (int i = 0; i < 4; ++i) red[sq + 8 * i][oq] = partial[i];
    __syncthreads();
    if (tid < TS) {
        float sum = 0.f;
#pragma unroll
        for (int k = 0; k < 64; ++k) sum += red[tid][k];
        const int s = s0 + tid;
        const float sc = (mask[(size_t)b * S + s] == 0) ? -1e10f : sum;
        scores[(size_t)b * S + s] = sc;
    }
}

// ---------------------------------------------------------------------------
// Kernel 3: softmax over S per batch row. One block per b.
// ---------------------------------------------------------------------------
__global__ __launch_bounds__(256) void k_softmax(const float* __restrict__ scores,
                                                 float* __restrict__ out) {
    const int b = blockIdx.x;
    const int tid = threadIdx.x;
    __shared__ float sm[64];
    float v[4];
    float mx = -INFINITY;
#pragma unroll
    for (int k = 0; k < 4; ++k) {
        v[k] = scores[(size_t)b * S + tid + k * 256];
        mx = fmaxf(mx, v[k]);
    }
#pragma unroll
    for (int off = 32; off > 0; off >>= 1) mx = fmaxf(mx, __shfl_down(mx, off, 64));
    if ((tid & 63) == 0) sm[tid >> 6] = mx;
    __syncthreads();
    if (tid == 0) {
        float m = sm[0];
        for (int k = 1; k < 4; ++k) m = fmaxf(m, sm[k]);
        sm[4] = m;
    }
    __syncthreads();
    mx = sm[4];
    float sum = 0.f;
#pragma unroll
    for (int k = 0; k < 4; ++k) { v[k] = __expf(v[k] - mx); sum += v[k]; }
#pragma unroll
    for (int off = 32; off > 0; off >>= 1) sum += __shfl_down(sum, off, 64);
    if ((tid & 63) == 0) sm[8 + (tid >> 6)] = sum;
    __syncthreads();
    if (tid == 0) sm[12] = sm[8] + sm[9] + sm[10] + sm[11];
    __syncthreads();
    const float inv = 1.f / sm[12];
#pragma unroll
    for (int k = 0; k < 4; ++k) out[(size_t)b * S + tid + k * 256] = v[k] * inv;
}

// ---------------------------------------------------------------------------
extern "C" void kernel_launch(void* const* d_in, const int* in_sizes, int n_in,
                              void* d_out, int out_size, void* d_ws, size_t ws_size,
                              hipStream_t stream) {
    const float* hidden = (const float*)d_in[0];   // (B,H)
    const float* enc    = (const float*)d_in[1];   // (S,B,H)
    const int*   mask   = (const int*)d_in[2];     // (B,S)
    const float* attn_W = (const float*)d_in[3];   // (H,2H)
    const float* attn_b = (const float*)d_in[4];   // (H,)
    const float* v_W    = (const float*)d_in[5];   // (H,)
    float* out = (float*)d_out;                    // (B,S)

    float* hb     = (float*)d_ws;                  // B*H floats
    float* scores = hb + (size_t)B * H;            // B*S floats

    // hb = hidden @ Wh^T + attn_b   (one wave per (b,o))
    k_hproj<<<dim3((B * H) / 4), 256, 0, stream>>>(hidden, attn_W, attn_b, hb);

    // fused energy + scores
    k_energy<<<dim3(S / TS, B), 512, 0, stream>>>(enc, attn_W, v_W, hb, mask, scores);

    // softmax over S
    k_softmax<<<dim3(B), 256, 0, stream>>>(scores, out);
}

// Round 5
// 270.552 us; speedup vs baseline: 9.5382x; 9.5382x over previous
//
#include <hip/hip_runtime.h>
#include <hip/hip_bf16.h>
#include <math.h>

constexpr int B = 64, S = 1024, H = 1024;

typedef __attribute__((ext_vector_type(8))) short bf16x8;
typedef __attribute__((ext_vector_type(4))) float f32x4;

// f32 -> bf16 (round-to-nearest-even), branchless
__device__ __forceinline__ short f2bf(float f) {
    unsigned u = __builtin_bit_cast(unsigned, f);
    unsigned r = (u + 0x7fffu + ((u >> 16) & 1u)) >> 16;
    return (short)r;
}

__device__ __forceinline__ float tanh_fast(float x) {
    // tanh(x) = 1 - 2/(e^{2x}+1); well-behaved at +-inf of expf
    return 1.0f - 2.0f / (__expf(2.0f * x) + 1.0f);
}

__device__ __forceinline__ void gload_lds16(const void* g, void* l) {
    __builtin_amdgcn_global_load_lds(
        (const __attribute__((address_space(1))) unsigned int*)g,
        (__attribute__((address_space(3))) unsigned int*)(uintptr_t)l,
        16, 0, 0);
}

// ---------------------------------------------------------------------------
// Kernel 1: hb[b][o] = attn_b[o] + sum_h hidden[b,h] * attn_W[o,h]   (f32)
// ---------------------------------------------------------------------------
__global__ __launch_bounds__(256) void k_hproj(const float* __restrict__ hidden,
                                               const float* __restrict__ attn_W,
                                               const float* __restrict__ attn_b,
                                               float* __restrict__ hb) {
    int wid  = blockIdx.x * 4 + (threadIdx.x >> 6);
    int lane = threadIdx.x & 63;
    int b = wid >> 10;
    int o = wid & 1023;
    const float* hrow = hidden + (size_t)b * H;
    const float* wrow = attn_W + (size_t)o * (2 * H);
    float acc = 0.f;
#pragma unroll
    for (int k = 0; k < 4; ++k) {
        int idx = lane * 4 + k * 256;
        float4 hv = *(const float4*)(hrow + idx);
        float4 wv = *(const float4*)(wrow + idx);
        acc += hv.x * wv.x + hv.y * wv.y + hv.z * wv.z + hv.w * wv.w;
    }
#pragma unroll
    for (int off = 32; off > 0; off >>= 1) acc += __shfl_down(acc, off, 64);
    if (lane == 0) hb[(size_t)b * H + o] = acc + attn_b[o];
}

// ---------------------------------------------------------------------------
// Kernel 2: convert We = attn_W[:, H:] -> bf16, stored pre-swizzled in
// LDS-consumption order: granule layout ((nb*16+ks)*512 + n)*8 + (g ^ (n&7)),
// each granule = 8 bf16 = 16B, holding We[nb*512+n][ks*64 + g*8 .. +7].
// ---------------------------------------------------------------------------
__global__ __launch_bounds__(256) void k_convW(const float* __restrict__ attn_W,
                                               short* __restrict__ WeB) {
    int gid = blockIdx.x * 256 + threadIdx.x;     // granule id, 131072 total
    int n     = (gid >> 3) & 511;
    int gphys = gid & 7;
    int glog  = gphys ^ (n & 7);
    int nb = gid >> 16;
    int ks = (gid >> 12) & 15;
    int o  = nb * 512 + n;
    int k0 = ks * 64 + glog * 8;
    const float* src = attn_W + (size_t)o * (2 * H) + H + k0;
    float4 v0 = *(const float4*)src;
    float4 v1 = *(const float4*)(src + 4);
    bf16x8 pk;
    pk[0] = f2bf(v0.x); pk[1] = f2bf(v0.y); pk[2] = f2bf(v0.z); pk[3] = f2bf(v0.w);
    pk[4] = f2bf(v1.x); pk[5] = f2bf(v1.y); pk[6] = f2bf(v1.z); pk[7] = f2bf(v1.w);
    *(bf16x8*)(WeB + (size_t)gid * 8) = pk;
}

// ---------------------------------------------------------------------------
// Kernel 3: MFMA energy GEMM fused with tanh + v_W-dot epilogue.
// Grid: (M/64 = 1024, nb = 2). Block 512 thr = 8 waves, each wave a 64x64 tile.
// A (enc rows, f32) reg-staged with inline bf16 convert; B (WeB) via
// global_load_lds from the pre-swizzled panel. Double-buffered, BK=64.
// ---------------------------------------------------------------------------
__global__ __launch_bounds__(512, 1) void k_mfma(const float* __restrict__ enc,
                                                 const short* __restrict__ WeB,
                                                 const float* __restrict__ v_W,
                                                 const float* __restrict__ hb,
                                                 float* __restrict__ pscore) {
    __shared__ short Abuf[2][64 * 64];    // 16 KB
    __shared__ short Bbuf[2][512 * 64];   // 128 KB
    __shared__ float red[64][8];          // 2 KB

    const int tid  = threadIdx.x;
    const int lane = tid & 63;
    const int wv   = tid >> 6;
    const int t16  = lane & 15;
    const int q    = lane >> 4;
    const int Mtile = blockIdx.x;
    const int nb    = blockIdx.y;
    const int b  = Mtile >> 4;
    const int s0 = (Mtile & 15) * 64;

    // staging roles
    const int am = tid >> 3;      // A row 0..63
    const int ag = tid & 7;       // A granule 0..7
    const float* abase = enc + ((size_t)(s0 + am) * B + b) * H + ag * 8;
    const char* bpanel0 = (const char*)WeB + ((size_t)(nb * 16) << 16); // 64KB per ks

    f32x4 acc[4][4];
#pragma unroll
    for (int mf = 0; mf < 4; ++mf)
#pragma unroll
        for (int nf = 0; nf < 4; ++nf) acc[mf][nf] = (f32x4){0.f, 0.f, 0.f, 0.f};

    const int nwv = wv * 64;
    const int swz = (t16 & 7);        // XOR term for frag reads
    const int aswz = ag ^ (am & 7);   // physical granule for A writes

    // ---- prologue: stage k-step 0 into buf 0
    {
        const char* bsrc = bpanel0;
#pragma unroll
        for (int r = 0; r < 8; ++r)
            gload_lds16(bsrc + (r * 512 + tid) * 16,
                        (char*)&Bbuf[0][0] + (r * 512 + tid) * 16);
        float4 v0 = *(const float4*)(abase);
        float4 v1 = *(const float4*)(abase + 4);
        bf16x8 pk;
        pk[0] = f2bf(v0.x); pk[1] = f2bf(v0.y); pk[2] = f2bf(v0.z); pk[3] = f2bf(v0.w);
        pk[4] = f2bf(v1.x); pk[5] = f2bf(v1.y); pk[6] = f2bf(v1.z); pk[7] = f2bf(v1.w);
        *(bf16x8*)&Abuf[0][am * 64 + aswz * 8] = pk;
    }
    __syncthreads();

    // ---- main K loop: 16 steps of BK=64
    for (int ks = 0; ks < 16; ++ks) {
        const int cur = ks & 1;
        const int nxt = cur ^ 1;
        float4 v0, v1;
        const bool pf = (ks < 15);
        if (pf) {
            // T14 issue-early: A global loads to regs
            const float* asrc = abase + (ks + 1) * 64;
            v0 = *(const float4*)(asrc);
            v1 = *(const float4*)(asrc + 4);
            // B async direct-to-LDS (double buffer selected by compile-visible xor)
            const char* bsrc = bpanel0 + ((size_t)(ks + 1) << 16);
            if (nxt) {
#pragma unroll
                for (int r = 0; r < 8; ++r)
                    gload_lds16(bsrc + (r * 512 + tid) * 16,
                                (char*)&Bbuf[1][0] + (r * 512 + tid) * 16);
            } else {
#pragma unroll
                for (int r = 0; r < 8; ++r)
                    gload_lds16(bsrc + (r * 512 + tid) * 16,
                                (char*)&Bbuf[0][0] + (r * 512 + tid) * 16);
            }
        }

        // compute on buf[cur]
        const short* Ab = &Abuf[cur][0];
        const short* Bb = &Bbuf[cur][0];
#pragma unroll
        for (int kh = 0; kh < 2; ++kh) {
            const int gq = kh * 4 + q;        // logical granule 0..7
            const int gp = (gq ^ swz) * 8;    // physical bf16 offset within row
            bf16x8 af[4], bfr[4];
#pragma unroll
            for (int mf = 0; mf < 4; ++mf)
                af[mf] = *(const bf16x8*)(Ab + (mf * 16 + t16) * 64 + gp);
#pragma unroll
            for (int nf = 0; nf < 4; ++nf)
                bfr[nf] = *(const bf16x8*)(Bb + (nwv + nf * 16 + t16) * 64 + gp);
#pragma unroll
            for (int mf = 0; mf < 4; ++mf)
#pragma unroll
                for (int nf = 0; nf < 4; ++nf)
                    acc[mf][nf] = __builtin_amdgcn_mfma_f32_16x16x32_bf16(
                        af[mf], bfr[nf], acc[mf][nf], 0, 0, 0);
        }

        if (pf) {
            // T14 write-late: convert + ds_write into next buffer
            bf16x8 pk;
            pk[0] = f2bf(v0.x); pk[1] = f2bf(v0.y); pk[2] = f2bf(v0.z); pk[3] = f2bf(v0.w);
            pk[4] = f2bf(v1.x); pk[5] = f2bf(v1.y); pk[6] = f2bf(v1.z); pk[7] = f2bf(v1.w);
            *(bf16x8*)&Abuf[nxt][am * 64 + aswz * 8] = pk;
        }
        __syncthreads();
    }

    // ---- epilogue: tanh + v_W dot, reduce over all 512 cols of this nb
    float psum[4][4];
#pragma unroll
    for (int mf = 0; mf < 4; ++mf)
#pragma unroll
        for (int r = 0; r < 4; ++r) psum[mf][r] = 0.f;

#pragma unroll
    for (int nf = 0; nf < 4; ++nf) {
        const int o = nb * 512 + nwv + nf * 16 + t16;
        const float hbv = hb[(size_t)b * H + o];
        const float vw  = v_W[o];
#pragma unroll
        for (int mf = 0; mf < 4; ++mf)
#pragma unroll
            for (int r = 0; r < 4; ++r)
                psum[mf][r] += vw * tanh_fast(acc[mf][nf][r] + hbv);
    }
    // reduce across the 16 lanes (t16) sharing the same rows
#pragma unroll
    for (int mf = 0; mf < 4; ++mf)
#pragma unroll
        for (int r = 0; r < 4; ++r) {
#pragma unroll
            for (int off = 1; off < 16; off <<= 1)
                psum[mf][r] += __shfl_xor(psum[mf][r], off, 64);
        }
    if (t16 == 0) {
#pragma unroll
        for (int mf = 0; mf < 4; ++mf)
#pragma unroll
            for (int r = 0; r < 4; ++r)
                red[mf * 16 + q * 4 + r][wv] = psum[mf][r];
    }
    __syncthreads();
    if (tid < 64) {
        float s = 0.f;
#pragma unroll
        for (int w = 0; w < 8; ++w) s += red[tid][w];
        pscore[(size_t)nb * (B * S) + (size_t)Mtile * 64 + tid] = s;
    }
}

// ---------------------------------------------------------------------------
// Kernel 4: combine partials + mask + softmax over S. One block per b.
// ---------------------------------------------------------------------------
__global__ __launch_bounds__(256) void k_softmax(const float* __restrict__ pscore,
                                                 const int* __restrict__ mask,
                                                 float* __restrict__ out) {
    const int b = blockIdx.x;
    const int tid = threadIdx.x;
    __shared__ float sm[64];
    float v[4];
    float mx = -INFINITY;
#pragma unroll
    for (int k = 0; k < 4; ++k) {
        const int s = tid + k * 256;
        const size_t idx = (size_t)b * S + s;
        float sc = pscore[idx] + pscore[(size_t)(B * S) + idx];
        sc = (mask[idx] == 0) ? -1e10f : sc;
        v[k] = sc;
        mx = fmaxf(mx, sc);
    }
#pragma unroll
    for (int off = 32; off > 0; off >>= 1) mx = fmaxf(mx, __shfl_down(mx, off, 64));
    if ((tid & 63) == 0) sm[tid >> 6] = mx;
    __syncthreads();
    if (tid == 0) {
        float m = sm[0];
        for (int k = 1; k < 4; ++k) m = fmaxf(m, sm[k]);
        sm[4] = m;
    }
    __syncthreads();
    mx = sm[4];
    float sum = 0.f;
#pragma unroll
    for (int k = 0; k < 4; ++k) { v[k] = __expf(v[k] - mx); sum += v[k]; }
#pragma unroll
    for (int off = 32; off > 0; off >>= 1) sum += __shfl_down(sum, off, 64);
    if ((tid & 63) == 0) sm[8 + (tid >> 6)] = sum;
    __syncthreads();
    if (tid == 0) sm[12] = sm[8] + sm[9] + sm[10] + sm[11];
    __syncthreads();
    const float inv = 1.f / sm[12];
#pragma unroll
    for (int k = 0; k < 4; ++k) out[(size_t)b * S + tid + k * 256] = v[k] * inv;
}

// ---------------------------------------------------------------------------
extern "C" void kernel_launch(void* const* d_in, const int* in_sizes, int n_in,
                              void* d_out, int out_size, void* d_ws, size_t ws_size,
                              hipStream_t stream) {
    const float* hidden = (const float*)d_in[0];   // (B,H)
    const float* enc    = (const float*)d_in[1];   // (S,B,H)
    const int*   mask   = (const int*)d_in[2];     // (B,S)
    const float* attn_W = (const float*)d_in[3];   // (H,2H)
    const float* attn_b = (const float*)d_in[4];   // (H,)
    const float* v_W    = (const float*)d_in[5];   // (H,)
    float* out = (float*)d_out;                    // (B,S)

    float* hb     = (float*)d_ws;                          // 64K f32   (256 KB)
    short* WeB    = (short*)(hb + (size_t)B * H);          // 1M bf16   (2 MB)
    float* pscore = (float*)(WeB + (size_t)H * H);         // 128K f32  (512 KB)

    k_hproj<<<dim3((B * H) / 4), 256, 0, stream>>>(hidden, attn_W, attn_b, hb);
    k_convW<<<dim3(512), 256, 0, stream>>>(attn_W, WeB);
    k_mfma<<<dim3((B * S) / 64, 2), 512, 0, stream>>>(enc, WeB, v_W, hb, pscore);
    k_softmax<<<dim3(B), 256, 0, stream>>>(pscore, mask, out);
}